// Round 8
// baseline (750.842 us; speedup 1.0000x reference)
//
#include <hip/hip_runtime.h>
#include <hip/hip_bf16.h>

#define IN_DIM  512
#define HID     1024
#define OUT_DIM 512
#define BATCH   4096
#define T_STEPS 32

typedef __attribute__((ext_vector_type(8))) short bf16x8;
typedef __attribute__((ext_vector_type(4))) float f32x4;

__device__ inline void gload16(const void* g, void* l) {
  __builtin_amdgcn_global_load_lds(
      (const __attribute__((address_space(1))) void*)g,
      (__attribute__((address_space(3))) void*)l, 16, 0, 0);
}

// Two 16B A-fragment loads (ks=0 at +0, ks=1 at +64B) straight to VGPRs.
// asm so OUR counted vmcnt governs them (compiler inserts no waits for asm
// defs); "memory" pins issue order vs the gload16 builtins (vmcnt counting).
__device__ inline void aload2(bf16x8 &d0, bf16x8 &d1, const __hip_bfloat16* p) {
  asm volatile("global_load_dwordx4 %0, %2, off\n\t"
               "global_load_dwordx4 %1, %2, off offset:64"
               : "=&v"(d0), "=&v"(d1)
               : "v"(p)
               : "memory");
}

// D[b][i] = sum_k A[b][k] * B[i][k], then relu(D + bias[i]).
// Tile 128(b) x 64(i), BK=64, 4 waves stacked in M (wave tile 32b x 64i,
// acc[2][4]), 2 blocks/CU.
// NEW (R8): A never touches LDS. Each A row belongs to exactly one wave, so
// A fragments are loaded global->VGPR (depth-2 register dbuf, inline-asm
// dwordx4). B stays LDS-staged (each B row read by all 4 waves) with the R4
// counted-vmcnt skeleton + T2 both-sides XOR swizzle + T5 setprio.
// vmcnt ledger (issue order B(t) | A(t) | B(t+1)):
//   top of iter t: vmcnt(2)  -> B(t)+A(t) drained, B(t+1)'s 2 in flight.
// XCD-stable batch panels (R7) + nt-stores for Cf (R7) retained.
// A: [4096][K] bf16 row-major; B: [Ntot][K] bf16 row-major (k-contiguous)
// Cf: f32 transposed Cf[i*BATCH+b]; Cb: bf16 Cb[b*Nld+i] (may be null)
__global__ __launch_bounds__(256, 2) void gemm_bt_bias_relu(
    const __hip_bfloat16* __restrict__ A,
    const __hip_bfloat16* __restrict__ B,
    const float* __restrict__ bias,
    float* __restrict__ Cf,
    __hip_bfloat16* __restrict__ Cb,
    int K, int Nld, int nx)
{
  // bijective XCD swizzle (nwg % 8 == 0: 512 or 256)
  const int nwg = gridDim.x;
  const int q   = nwg >> 3;
  const int bid = blockIdx.x;
  const int swz = (bid & 7) * q + (bid >> 3);
  const int bxi = swz % nx;          // neuron-tile index
  const int byi = swz / nx;          // batch-panel index (stable per XCD)
  const int brow = byi * 128;
  const int bcol = bxi * 64;

  const int tid  = threadIdx.x;
  const int lane = tid & 63;
  const int wid  = tid >> 6;          // 0..3, M-stacked waves
  const int l15  = lane & 15, l4 = lane >> 4;
  const int srow = lane >> 3;
  const int schunk = (lane & 7) ^ (srow & 7);   // T2 stage-side pre-swizzle

  __shared__ __hip_bfloat16 Blds[2][64 * 64];   // 2 x 8 KB

  f32x4 acc[2][4] = {};
  const int nt = K >> 6;   // 8 or 16 (even)

  // B staging: 2 gload16 per wave per tile
  auto stageB = [&](int ti, int buf) {
    const int kt = ti << 6;
#pragma unroll
    for (int it = 0; it < 2; ++it) {
      const int rowbase = it * 32 + wid * 8;          // wave-uniform LDS base
      gload16(B + (size_t)(bcol + rowbase + srow) * K + kt + schunk * 8,
              &Blds[buf][rowbase * 64]);
    }
  };

  // A fragment bases: row = brow + wid*32 + m*16 + l15, chunk = l4*8 elems
  const __hip_bfloat16* abase0 = A + (size_t)(brow + wid * 32 + l15) * K + l4 * 8;
  const __hip_bfloat16* abase1 = abase0 + (size_t)16 * K;

  // two named register banks for A (rule 20: no runtime indexing)
  bf16x8 xa00, xa01, xa10, xa11;   // bank X: frags (m, ks)
  bf16x8 ya00, ya01, ya10, ya11;   // bank Y

  // ---- prologue: B(0) | A(0)->X | B(1), order pinned for the ledger ----
  stageB(0, 0);
  __builtin_amdgcn_sched_barrier(0);
  aload2(xa00, xa01, abase0);
  aload2(xa10, xa11, abase1);
  __builtin_amdgcn_sched_barrier(0);
  stageB(1, 1);

  const int rx7 = l15 & 7;

  // one pipeline iteration; cur = A bank for tile ti, nxt = bank for ti+1
  auto iter = [&](int ti,
                  const bf16x8 &ca00, const bf16x8 &ca01,
                  const bf16x8 &ca10, const bf16x8 &ca11,
                  bf16x8 &na00, bf16x8 &na01, bf16x8 &na10, bf16x8 &na11) {
    const int buf = ti & 1;
    if (ti < nt - 1) {
      asm volatile("s_waitcnt vmcnt(2)" ::: "memory");   // B(ti)+A(ti) done
    } else {
      asm volatile("s_waitcnt vmcnt(0)" ::: "memory");
    }
    __builtin_amdgcn_s_barrier();
    __builtin_amdgcn_sched_barrier(0);

    // issue A(ti+1) into the other bank; hides under this iter's MFMA
    if (ti + 1 < nt) {
      const int koff = (ti + 1) << 6;
      aload2(na00, na01, abase0 + koff);
      aload2(na10, na11, abase1 + koff);
    }

    __builtin_amdgcn_s_setprio(1);
#pragma unroll
    for (int ks = 0; ks < 2; ++ks) {
      bf16x8 bfr[4];
      const int cp = ((ks * 4 + l4) ^ rx7) * 8;   // T2 read-side XOR
#pragma unroll
      for (int n = 0; n < 4; ++n)
        bfr[n] = *(const bf16x8*)&Blds[buf][(n * 16 + l15) * 64 + cp];
      const bf16x8 &af0 = ks ? ca01 : ca00;
      const bf16x8 &af1 = ks ? ca11 : ca10;
#pragma unroll
      for (int n = 0; n < 4; ++n) {
        acc[0][n] = __builtin_amdgcn_mfma_f32_16x16x32_bf16(af0, bfr[n], acc[0][n], 0, 0, 0);
        acc[1][n] = __builtin_amdgcn_mfma_f32_16x16x32_bf16(af1, bfr[n], acc[1][n], 0, 0, 0);
      }
    }
    __builtin_amdgcn_s_setprio(0);

    asm volatile("s_waitcnt lgkmcnt(0)" ::: "memory");   // B reads of buf done
    __builtin_amdgcn_sched_barrier(0);
    __builtin_amdgcn_s_barrier();
    __builtin_amdgcn_sched_barrier(0);
    if (ti + 2 < nt) stageB(ti + 2, buf);                // refill consumed buf
  };

  for (int ti = 0; ti < nt; ti += 2) {
    iter(ti,     xa00, xa01, xa10, xa11,  ya00, ya01, ya10, ya11);
    iter(ti + 1, ya00, ya01, ya10, ya11,  xa00, xa01, xa10, xa11);
  }

  // ---- epilogue: bias + relu, dual store ----
#pragma unroll
  for (int n = 0; n < 4; ++n) {
    const int i = bcol + n * 16 + l15;
    const float bv = bias[i];
#pragma unroll
    for (int m = 0; m < 2; ++m) {
      const int b0 = brow + wid * 32 + m * 16 + l4 * 4;
      f32x4 v = acc[m][n];
      f32x4 o;
      o[0] = fmaxf(v[0] + bv, 0.0f);
      o[1] = fmaxf(v[1] + bv, 0.0f);
      o[2] = fmaxf(v[2] + bv, 0.0f);
      o[3] = fmaxf(v[3] + bv, 0.0f);
      // itm/out never re-read by the GEMM chain: bypass L2
      __builtin_nontemporal_store(o, (f32x4*)(Cf + (size_t)i * BATCH + b0));
      if (Cb) {
        // h^T IS re-read next step from this XCD's L2: cached stores
        Cb[(size_t)(b0 + 0) * Nld + i] = __float2bfloat16(o[0]);
        Cb[(size_t)(b0 + 1) * Nld + i] = __float2bfloat16(o[1]);
        Cb[(size_t)(b0 + 2) * Nld + i] = __float2bfloat16(o[2]);
        Cb[(size_t)(b0 + 3) * Nld + i] = __float2bfloat16(o[3]);
      }
    }
  }
}

// plain f32 -> bf16 convert (vectorized), n4 = count/4
__global__ __launch_bounds__(256) void f32_to_bf16(
    const float* __restrict__ in, __hip_bfloat16* __restrict__ out, int n4)
{
  int i = blockIdx.x * blockDim.x + threadIdx.x;
  if (i < n4) {
    float4 v = ((const float4*)in)[i];
    union { __hip_bfloat16 h[4]; ushort4 u; } p;
    p.h[0] = __float2bfloat16(v.x);
    p.h[1] = __float2bfloat16(v.y);
    p.h[2] = __float2bfloat16(v.z);
    p.h[3] = __float2bfloat16(v.w);
    ((ushort4*)out)[i] = p.u;
  }
}

// in[R][C] f32 -> out[C][R] bf16 (LDS 32x32 tile transpose)
__global__ __launch_bounds__(256) void transpose_f32_bf16(
    const float* __restrict__ in, __hip_bfloat16* __restrict__ out, int R, int C)
{
  __shared__ float tile[32][33];
  const int c0 = blockIdx.x * 32, r0 = blockIdx.y * 32;
  const int tx = threadIdx.x & 31, ty = threadIdx.x >> 5;
#pragma unroll
  for (int dy = 0; dy < 32; dy += 8)
    tile[ty + dy][tx] = in[(size_t)(r0 + ty + dy) * C + c0 + tx];
  __syncthreads();
#pragma unroll
  for (int dy = 0; dy < 32; dy += 8)
    out[(size_t)(c0 + ty + dy) * R + r0 + tx] = __float2bfloat16(tile[tx][ty + dy]);
}

extern "C" void kernel_launch(void* const* d_in, const int* in_sizes, int n_in,
                              void* d_out, int out_size, void* d_ws, size_t ws_size,
                              hipStream_t stream)
{
  const float* x     = (const float*)d_in[0];   // [512][4096]
  const float* W_in  = (const float*)d_in[1];   // [1024][512]
  const float* b_in  = (const float*)d_in[2];   // [1024]
  const float* W_rec = (const float*)d_in[3];   // [1024][1024]
  const float* b_rec = (const float*)d_in[4];   // [1024]
  const float* W_out = (const float*)d_in[5];   // [512][1024]
  const float* b_out = (const float*)d_in[6];   // [512]

  float* out0 = (float*)d_out;                        // [512][4096]
  float* itm  = out0 + (size_t)OUT_DIM * BATCH;       // [33][1024][4096]

  __hip_bfloat16* xT = (__hip_bfloat16*)d_ws;         // [4096][512]
  __hip_bfloat16* Wi = xT + (size_t)BATCH * IN_DIM;   // [1024][512]
  __hip_bfloat16* Wr = Wi + (size_t)HID * IN_DIM;     // [1024][1024]
  __hip_bfloat16* Wo = Wr + (size_t)HID * HID;        // [512][1024]
  __hip_bfloat16* h0 = Wo + (size_t)OUT_DIM * HID;    // [4096][1024]
  __hip_bfloat16* h1 = h0 + (size_t)BATCH * HID;      // [4096][1024]

  // input conversions
  transpose_f32_bf16<<<dim3(BATCH / 32, IN_DIM / 32), 256, 0, stream>>>(x, xT, IN_DIM, BATCH);
  {
    int n4 = HID * IN_DIM / 4;
    f32_to_bf16<<<(n4 + 255) / 256, 256, 0, stream>>>(W_in, Wi, n4);
  }
  {
    int n4 = HID * HID / 4;
    f32_to_bf16<<<(n4 + 255) / 256, 256, 0, stream>>>(W_rec, Wr, n4);
  }
  {
    int n4 = OUT_DIM * HID / 4;
    f32_to_bf16<<<(n4 + 255) / 256, 256, 0, stream>>>(W_out, Wo, n4);
  }

  // y0 = relu(W_in @ x + b_in): grid 512, nx = 16
  gemm_bt_bias_relu<<<(HID / 64) * (BATCH / 128), 256, 0, stream>>>(
      xT, Wi, b_in, itm, h0, IN_DIM, HID, HID / 64);

  // 32 recurrent steps
  __hip_bfloat16* cur = h0;
  __hip_bfloat16* nxt = h1;
  for (int t = 0; t < T_STEPS; ++t) {
    float* dst = itm + (size_t)(t + 1) * HID * BATCH;
    gemm_bt_bias_relu<<<(HID / 64) * (BATCH / 128), 256, 0, stream>>>(
        cur, Wr, b_rec, dst, nxt, HID, HID, HID / 64);
    __hip_bfloat16* tmp = cur; cur = nxt; nxt = tmp;
  }

  // out = relu(W_out @ h_last + b_out): grid 256, nx = 8
  gemm_bt_bias_relu<<<(OUT_DIM / 64) * (BATCH / 128), 256, 0, stream>>>(
      cur, Wo, b_out, out0, (__hip_bfloat16*)nullptr, HID, 0, OUT_DIM / 64);
}

// Round 10
// 594.778 us; speedup vs baseline: 1.2624x; 1.2624x over previous
//
#include <hip/hip_runtime.h>
#include <hip/hip_bf16.h>

#define IN_DIM  512
#define HID     1024
#define OUT_DIM 512
#define BATCH   4096
#define T_STEPS 32

typedef __attribute__((ext_vector_type(8))) short bf16x8;
typedef __attribute__((ext_vector_type(4))) float f32x4;

__device__ inline void gload16(const void* g, void* l) {
  __builtin_amdgcn_global_load_lds(
      (const __attribute__((address_space(1))) void*)g,
      (__attribute__((address_space(3))) void*)l, 16, 0, 0);
}

// D[b][i] = sum_k A[b][k] * B[i][k], then relu(D + bias[i]).
// R7 structure: tile 128(b) x 64(i), BK=64, 4 waves (2x2), 2 blocks/CU;
// T4 counted vmcnt depth-2 (vmcnt(6), never 0 in loop) + raw s_barrier pair;
// T2 both-sides XOR swizzle; T5 setprio; XCD-stable batch panels; nt-store Cf.
// NEW (R10): Cb (h^T) epilogue bounced through LDS -> full-sector coalesced
// global writes (was: 32B half-sector scatter, ~2x write amplification).
// A: [4096][K] bf16 row-major; B: [Ntot][K] bf16 row-major (k-contiguous)
// Cf: f32 transposed Cf[i*BATCH+b]; Cb: bf16 Cb[b*Nld+i] (may be null)
__global__ __launch_bounds__(256, 2) void gemm_bt_bias_relu(
    const __hip_bfloat16* __restrict__ A,
    const __hip_bfloat16* __restrict__ B,
    const float* __restrict__ bias,
    float* __restrict__ Cf,
    __hip_bfloat16* __restrict__ Cb,
    int K, int Nld, int nx)
{
  // bijective XCD swizzle (nwg % 8 == 0: 512 or 256)
  const int nwg = gridDim.x;
  const int q   = nwg >> 3;
  const int bid = blockIdx.x;
  const int swz = (bid & 7) * q + (bid >> 3);
  const int bxi = swz % nx;          // neuron-tile index
  const int byi = swz / nx;          // batch-panel index (stable per XCD)
  const int brow = byi * 128;
  const int bcol = bxi * 64;

  const int tid  = threadIdx.x;
  const int lane = tid & 63;
  const int wid  = tid >> 6;
  const int wr   = wid >> 1, wc = wid & 1;   // 2x2 waves: wave tile 64(b) x 32(i)
  const int l15  = lane & 15, l4 = lane >> 4;
  const int srow = lane >> 3;
  const int schunk = (lane & 7) ^ (srow & 7);   // T2 stage-side pre-swizzle

  __shared__ __hip_bfloat16 Alds[2][128 * 64];  // 2 x 16 KB
  __shared__ __hip_bfloat16 Blds[2][64 * 64];   // 2 x  8 KB

  f32x4 acc[4][2] = {};
  const int nt = K >> 6;   // 8 or 16, always >= 2

  // 6 gload16 per wave per tile (4 A + 2 B) -> vmcnt granularity of 6
  auto stage = [&](int ti, int buf) {
    const int kt = ti << 6;
#pragma unroll
    for (int it = 0; it < 4; ++it) {
      const int rowbase = it * 32 + wid * 8;           // wave-uniform LDS base
      gload16(A + (size_t)(brow + rowbase + srow) * K + kt + schunk * 8,
              &Alds[buf][rowbase * 64]);
    }
#pragma unroll
    for (int it = 0; it < 2; ++it) {
      const int rowbase = it * 32 + wid * 8;
      gload16(B + (size_t)(bcol + rowbase + srow) * K + kt + schunk * 8,
              &Blds[buf][rowbase * 64]);
    }
  };

  // ---- prologue: two tiles in flight ----
  stage(0, 0);
  stage(1, 1);

  const int rxor = l15 & 7;   // (row & 7) for all fragment rows this lane reads

  for (int ti = 0; ti < nt; ++ti) {
    const int buf = ti & 1;
    // T4: wait current tile's 6 loads; keep next tile's 6 in flight
    if (ti < nt - 1) {
      asm volatile("s_waitcnt vmcnt(6)" ::: "memory");
    } else {
      asm volatile("s_waitcnt vmcnt(0)" ::: "memory");
    }
    __builtin_amdgcn_s_barrier();
    __builtin_amdgcn_sched_barrier(0);   // rule 18: pin ds_reads below the wait

    __builtin_amdgcn_s_setprio(1);
#pragma unroll
    for (int ks = 0; ks < 2; ++ks) {
      bf16x8 af[4], bfr[2];
      const int cp = ((ks * 4 + l4) ^ rxor) * 8;   // T2 read-side XOR (16B chunks)
#pragma unroll
      for (int m = 0; m < 4; ++m)
        af[m] = *(const bf16x8*)&Alds[buf][(wr * 64 + m * 16 + l15) * 64 + cp];
#pragma unroll
      for (int n = 0; n < 2; ++n)
        bfr[n] = *(const bf16x8*)&Blds[buf][(wc * 32 + n * 16 + l15) * 64 + cp];
#pragma unroll
      for (int m = 0; m < 4; ++m)
#pragma unroll
        for (int n = 0; n < 2; ++n)
          acc[m][n] = __builtin_amdgcn_mfma_f32_16x16x32_bf16(af[m], bfr[n], acc[m][n], 0, 0, 0);
    }
    __builtin_amdgcn_s_setprio(0);

    asm volatile("s_waitcnt lgkmcnt(0)" ::: "memory");  // all reads of buf done
    __builtin_amdgcn_sched_barrier(0);
    __builtin_amdgcn_s_barrier();
    __builtin_amdgcn_sched_barrier(0);                  // pin stage below barrier
    if (ti < nt - 2) stage(ti + 2, buf);                // refill consumed buffer
  }

  // ---- epilogue: bias + relu ----
  // Cf: nt-store (never re-read). Cb: bounce through LDS (Alds[0] is free and
  // all waves passed the final lgkmcnt(0)+barrier) for full-sector writes.
  __hip_bfloat16* tileB = &Alds[0][0];   // 128*64 bf16 = 16 KB, [b][i] layout
#pragma unroll
  for (int n = 0; n < 2; ++n) {
    const int il = wc * 32 + n * 16 + l15;    // i within tile
    const int i  = bcol + il;
    const float bv = bias[i];
#pragma unroll
    for (int m = 0; m < 4; ++m) {
      const int bl = wr * 64 + m * 16 + l4 * 4;   // b within tile
      const int b0 = brow + bl;
      f32x4 v = acc[m][n];
      f32x4 o;
      o[0] = fmaxf(v[0] + bv, 0.0f);
      o[1] = fmaxf(v[1] + bv, 0.0f);
      o[2] = fmaxf(v[2] + bv, 0.0f);
      o[3] = fmaxf(v[3] + bv, 0.0f);
      __builtin_nontemporal_store(o, (f32x4*)(Cf + (size_t)i * BATCH + b0));
      if (Cb) {
        tileB[(bl + 0) * 64 + il] = __float2bfloat16(o[0]);
        tileB[(bl + 1) * 64 + il] = __float2bfloat16(o[1]);
        tileB[(bl + 2) * 64 + il] = __float2bfloat16(o[2]);
        tileB[(bl + 3) * 64 + il] = __float2bfloat16(o[3]);
      }
    }
  }
  if (Cb) {   // uniform branch (kernel arg) -> syncthreads is safe
    __syncthreads();
    // 8192 elems / 256 threads = 32 elems (4 x 16B chunks) per thread.
    // chunk index c = r*256 + tid: consecutive lanes -> consecutive 16B in
    // LDS (bank-striped) AND contiguous 128B runs per b-row in global.
#pragma unroll
    for (int r = 0; r < 4; ++r) {
      const int c   = r * 256 + tid;
      const int off = c * 8;               // element offset in tile
      const int b   = off >> 6, ii = off & 63;
      *(bf16x8*)(Cb + (size_t)(brow + b) * Nld + bcol + ii) =
          *(const bf16x8*)&tileB[off];
    }
  }
}

// fused f32 -> bf16 convert for the 3 weight matrices (dst contiguous in ws)
__global__ __launch_bounds__(256) void convert_weights(
    const float* __restrict__ w_in, const float* __restrict__ w_rec,
    const float* __restrict__ w_out, __hip_bfloat16* __restrict__ dst)
{
  const int i = blockIdx.x * blockDim.x + threadIdx.x;   // float4 index
  const int n1 = (HID * IN_DIM) / 4;          // 131072
  const int n2 = n1 + (HID * HID) / 4;        // 393216
  const int nT = n2 + (OUT_DIM * HID) / 4;    // 524288
  if (i >= nT) return;
  const float* src;
  int local;
  if (i < n1)       { src = w_in;  local = i; }
  else if (i < n2)  { src = w_rec; local = i - n1; }
  else              { src = w_out; local = i - n2; }
  float4 v = ((const float4*)src)[local];
  union { __hip_bfloat16 h[4]; ushort4 u; } p;
  p.h[0] = __float2bfloat16(v.x);
  p.h[1] = __float2bfloat16(v.y);
  p.h[2] = __float2bfloat16(v.z);
  p.h[3] = __float2bfloat16(v.w);
  ((ushort4*)dst)[i] = p.u;
}

// in[R][C] f32 -> out[C][R] bf16 (LDS 32x32 tile transpose)
__global__ __launch_bounds__(256) void transpose_f32_bf16(
    const float* __restrict__ in, __hip_bfloat16* __restrict__ out, int R, int C)
{
  __shared__ float tile[32][33];
  const int c0 = blockIdx.x * 32, r0 = blockIdx.y * 32;
  const int tx = threadIdx.x & 31, ty = threadIdx.x >> 5;
#pragma unroll
  for (int dy = 0; dy < 32; dy += 8)
    tile[ty + dy][tx] = in[(size_t)(r0 + ty + dy) * C + c0 + tx];
  __syncthreads();
#pragma unroll
  for (int dy = 0; dy < 32; dy += 8)
    out[(size_t)(c0 + ty + dy) * R + r0 + tx] = __float2bfloat16(tile[tx][ty + dy]);
}

extern "C" void kernel_launch(void* const* d_in, const int* in_sizes, int n_in,
                              void* d_out, int out_size, void* d_ws, size_t ws_size,
                              hipStream_t stream)
{
  const float* x     = (const float*)d_in[0];   // [512][4096]
  const float* W_in  = (const float*)d_in[1];   // [1024][512]
  const float* b_in  = (const float*)d_in[2];   // [1024]
  const float* W_rec = (const float*)d_in[3];   // [1024][1024]
  const float* b_rec = (const float*)d_in[4];   // [1024]
  const float* W_out = (const float*)d_in[5];   // [512][1024]
  const float* b_out = (const float*)d_in[6];   // [512]

  float* out0 = (float*)d_out;                        // [512][4096]
  float* itm  = out0 + (size_t)OUT_DIM * BATCH;       // [33][1024][4096]

  __hip_bfloat16* xT = (__hip_bfloat16*)d_ws;         // [4096][512]
  __hip_bfloat16* Wi = xT + (size_t)BATCH * IN_DIM;   // [1024][512]
  __hip_bfloat16* Wr = Wi + (size_t)HID * IN_DIM;     // [1024][1024]
  __hip_bfloat16* Wo = Wr + (size_t)HID * HID;        // [512][1024]
  __hip_bfloat16* h0 = Wo + (size_t)OUT_DIM * HID;    // [4096][1024]
  __hip_bfloat16* h1 = h0 + (size_t)BATCH * HID;      // [4096][1024]

  // input conversions: transpose x, convert all 3 weights in one launch
  transpose_f32_bf16<<<dim3(BATCH / 32, IN_DIM / 32), 256, 0, stream>>>(x, xT, IN_DIM, BATCH);
  {
    const int nT = (HID * IN_DIM + HID * HID + OUT_DIM * HID) / 4;  // 524288
    convert_weights<<<(nT + 255) / 256, 256, 0, stream>>>(W_in, W_rec, W_out, Wi);
  }

  // y0 = relu(W_in @ x + b_in): grid 512, nx = 16
  gemm_bt_bias_relu<<<(HID / 64) * (BATCH / 128), 256, 0, stream>>>(
      xT, Wi, b_in, itm, h0, IN_DIM, HID, HID / 64);

  // 32 recurrent steps
  __hip_bfloat16* cur = h0;
  __hip_bfloat16* nxt = h1;
  for (int t = 0; t < T_STEPS; ++t) {
    float* dst = itm + (size_t)(t + 1) * HID * BATCH;
    gemm_bt_bias_relu<<<(HID / 64) * (BATCH / 128), 256, 0, stream>>>(
        cur, Wr, b_rec, dst, nxt, HID, HID, HID / 64);
    __hip_bfloat16* tmp = cur; cur = nxt; nxt = tmp;
  }

  // out = relu(W_out @ h_last + b_out): grid 256, nx = 8
  gemm_bt_bias_relu<<<(OUT_DIM / 64) * (BATCH / 128), 256, 0, stream>>>(
      cur, Wo, b_out, out0, (__hip_bfloat16*)nullptr, HID, 0, OUT_DIM / 64);
}